// Round 6
// baseline (575.117 us; speedup 1.0000x reference)
//
#include <hip/hip_runtime.h>
#include <hip/hip_cooperative_groups.h>

namespace cg = cooperative_groups;

#define HH 160
#define WW 160
#define DD 16
#define NG 8192
#define VOXEL 0.4f

// tiles: 40 x 40 x 4, each 4x4x4 voxels = 6400 tiles, one WAVE (=block) per tile
#define TTX 40
#define TTY 40
#define TTZ 4
#define NTILES (TTX * TTY * TTZ)
#define CAP 128     // avg ~37 survivors/tile, +15 sigma tail << 128

#define TPB 64
#define BLOCKS 3072  // 12 blocks/CU * 256 CU; __launch_bounds__(64,3) guarantees residency

// d_ws layout:
//   packf    : (NG+1) * 16 floats (record 16 = sentinel)  @ 0       (524 KB)
//   tileCnt  : NTILES int                                  @ 528 KB
//   tileList : NTILES * CAP int                            @ 576 KB  (3.28 MB)
// pack record (16 floats): mu.xyz, op, bb.xyz, c00, c01, c02, c11, c12, c22, 0,0,0

__device__ __forceinline__ void eval_one(
    int gsel, const float* __restrict__ packf, const float* __restrict__ featf,
    float px, float py, float pz, float4* acc) {
  const float* pr = packf + (size_t)gsel * 16;
  float mux = pr[0], muy = pr[1], muz = pr[2], op = pr[3];
  float bbx = pr[4], bby = pr[5], bbz = pr[6];
  float c00 = pr[7], c01 = pr[8], c02 = pr[9];
  float c11 = pr[10], c12 = pr[11], c22 = pr[12];
  const float4* fr = (const float4*)featf + (size_t)min(gsel, NG - 1) * 8;
  float4 f0 = fr[0], f1 = fr[1], f2 = fr[2], f3 = fr[3];
  float4 f4 = fr[4], f5 = fr[5], f6 = fr[6], f7 = fr[7];

  float dx = px - mux, dy = py - muy, dz = pz - muz;
  bool in = (fabsf(dx) <= bbx) & (fabsf(dy) <= bby) & (fabsf(dz) <= bbz);
  float maha = c00 * dx * dx + c11 * dy * dy + c22 * dz * dz +
               2.f * (c01 * dx * dy + c02 * dx * dz + c12 * dy * dz);
  float w = in ? op * __expf(-0.5f * maha) : 0.f;
  acc[0].x += w * f0.x; acc[0].y += w * f0.y; acc[0].z += w * f0.z; acc[0].w += w * f0.w;
  acc[1].x += w * f1.x; acc[1].y += w * f1.y; acc[1].z += w * f1.z; acc[1].w += w * f1.w;
  acc[2].x += w * f2.x; acc[2].y += w * f2.y; acc[2].z += w * f2.z; acc[2].w += w * f2.w;
  acc[3].x += w * f3.x; acc[3].y += w * f3.y; acc[3].z += w * f3.z; acc[3].w += w * f3.w;
  acc[4].x += w * f4.x; acc[4].y += w * f4.y; acc[4].z += w * f4.z; acc[4].w += w * f4.w;
  acc[5].x += w * f5.x; acc[5].y += w * f5.y; acc[5].z += w * f5.z; acc[5].w += w * f5.w;
  acc[6].x += w * f6.x; acc[6].y += w * f6.y; acc[6].z += w * f6.z; acc[6].w += w * f6.w;
  acc[7].x += w * f7.x; acc[7].y += w * f7.y; acc[7].z += w * f7.z; acc[7].w += w * f7.w;
}

__global__ __launch_bounds__(TPB, 3) void gv_fused(
    const float* __restrict__ means, const float* __restrict__ opac,
    const float* __restrict__ scales, const float* __restrict__ rots,
    const float* __restrict__ featf,
    float* __restrict__ packf, int* __restrict__ tileCnt,
    int* __restrict__ tileList, float4* __restrict__ out) {
  cg::grid_group grid = cg::this_grid();
  int gtid = blockIdx.x * TPB + threadIdx.x;
  int gsz = gridDim.x * TPB;

  // ---- phase 0: zero tile counters, write sentinel record ----
  for (int t = gtid; t < NTILES; t += gsz) tileCnt[t] = 0;
  if (gtid == 0) {
    float* s = packf + (size_t)NG * 16;
#pragma unroll
    for (int z = 0; z < 16; z++) s[z] = 0.f;
    s[4] = -1.f; s[5] = -1.f; s[6] = -1.f;   // bb < 0 => in always false => w = 0
  }
  grid.sync();

  // ---- phase 1: precompute + bin ----
  int g = gtid;
  if (g < NG) {
    float qw = rots[g * 4 + 0], qx = rots[g * 4 + 1];
    float qy = rots[g * 4 + 2], qz = rots[g * 4 + 3];
    float inv = rsqrtf(qw * qw + qx * qx + qy * qy + qz * qz);
    qw *= inv; qx *= inv; qy *= inv; qz *= inv;
    float R[3][3];
    R[0][0] = 1.f - 2.f * (qy * qy + qz * qz);
    R[0][1] = 2.f * (qx * qy - qw * qz);
    R[0][2] = 2.f * (qx * qz + qw * qy);
    R[1][0] = 2.f * (qx * qy + qw * qz);
    R[1][1] = 1.f - 2.f * (qx * qx + qz * qz);
    R[1][2] = 2.f * (qy * qz - qw * qx);
    R[2][0] = 2.f * (qx * qz - qw * qy);
    R[2][1] = 2.f * (qy * qz + qw * qx);
    R[2][2] = 1.f - 2.f * (qx * qx + qy * qy);
    float sx = scales[g * 3 + 0], sy = scales[g * 3 + 1], sz = scales[g * 3 + 2];
    float s2[3] = {sx * sx, sy * sy, sz * sz};
    float is2[3] = {1.f / s2[0], 1.f / s2[1], 1.f / s2[2]};
    float cov00 = 0.f, cov11 = 0.f, cov22 = 0.f;
    float ci00 = 0.f, ci01 = 0.f, ci02 = 0.f, ci11 = 0.f, ci12 = 0.f, ci22 = 0.f;
#pragma unroll
    for (int c = 0; c < 3; c++) {
      cov00 += R[0][c] * R[0][c] * s2[c];
      cov11 += R[1][c] * R[1][c] * s2[c];
      cov22 += R[2][c] * R[2][c] * s2[c];
      ci00 += R[0][c] * R[0][c] * is2[c];
      ci01 += R[0][c] * R[1][c] * is2[c];
      ci02 += R[0][c] * R[2][c] * is2[c];
      ci11 += R[1][c] * R[1][c] * is2[c];
      ci12 += R[1][c] * R[2][c] * is2[c];
      ci22 += R[2][c] * R[2][c] * is2[c];
    }
    float mx = means[g * 3 + 0], my = means[g * 3 + 1], mz = means[g * 3 + 2];
    float bx = 3.f * sqrtf(cov00), by = 3.f * sqrtf(cov11), bz = 3.f * sqrtf(cov22);
    float* p = packf + (size_t)g * 16;
    p[0] = mx;  p[1] = my;  p[2] = mz;  p[3] = opac[g];
    p[4] = bx;  p[5] = by;  p[6] = bz;  p[7] = ci00;
    p[8] = ci01; p[9] = ci02; p[10] = ci11; p[11] = ci12;
    p[12] = ci22; p[13] = 0.f; p[14] = 0.f; p[15] = 0.f;

    const float eps = 1e-4f;
    int i0 = (int)ceilf((mx - bx + 32.f) * 2.5f - 0.5f - eps);
    int i1 = (int)floorf((mx + bx + 32.f) * 2.5f - 0.5f + eps);
    int j0 = (int)ceilf((my - by + 32.f) * 2.5f - 0.5f - eps);
    int j1 = (int)floorf((my + by + 32.f) * 2.5f - 0.5f + eps);
    int k0 = (int)ceilf((mz - bz + 1.f) * 2.5f - 0.5f - eps);
    int k1 = (int)floorf((mz + bz + 1.f) * 2.5f - 0.5f + eps);
    i0 = max(i0, 0); i1 = min(i1, HH - 1);
    j0 = max(j0, 0); j1 = min(j1, WW - 1);
    k0 = max(k0, 0); k1 = min(k1, DD - 1);
    if (i0 <= i1 && j0 <= j1 && k0 <= k1) {
      int ti0 = i0 >> 2, ti1 = i1 >> 2;
      int tj0 = j0 >> 2, tj1 = j1 >> 2;
      int tk0 = k0 >> 2, tk1 = k1 >> 2;
      for (int ti = ti0; ti <= ti1; ti++)
        for (int tj = tj0; tj <= tj1; tj++)
          for (int tk = tk0; tk <= tk1; tk++) {
            int t = (ti * TTY + tj) * TTZ + tk;
            int pos = atomicAdd(&tileCnt[t], 1);
            if (pos < CAP) tileList[t * CAP + pos] = g;
          }
    }
  }
  grid.sync();

  // ---- phase 2: persistent wave-per-tile voxelize ----
  int lane = threadIdx.x;
  int di = (lane >> 4) & 3, dj = (lane >> 2) & 3, dk = lane & 3;

  for (int t = blockIdx.x; t < NTILES; t += gridDim.x) {
    int ti = t / (TTY * TTZ);
    int rem = t - ti * (TTY * TTZ);
    int tj = rem / TTZ;
    int tk = rem - tj * TTZ;
    int i = ti * 4 + di, j = tj * 4 + dj, k = tk * 4 + dk;

    float px = (i + 0.5f) * VOXEL - 32.f;
    float py = (j + 0.5f) * VOXEL - 32.f;
    float pz = (k + 0.5f) * VOXEL - 1.f;

    int cnt = min(tileCnt[t], CAP);
    const int* lst = tileList + t * CAP;

    float4 acc[8];
#pragma unroll
    for (int f = 0; f < 8; f++) acc[f] = make_float4(0.f, 0.f, 0.f, 0.f);

    if (cnt > 0) {
      int idx[8], idxN[8];
#pragma unroll
      for (int u = 0; u < 8; u++) idx[u] = lst[u];   // slots 0..7 always in-row

      for (int base = 0; base < cnt; base += 8) {
        int nb = base + 8;
#pragma unroll
        for (int u = 0; u < 8; u++) idxN[u] = lst[min(nb + u, CAP - 1)];  // prefetch next chunk
#pragma unroll
        for (int u = 0; u < 8; u++) {
          int gsel = (base + u < cnt) ? idx[u] : NG;  // branch-free pad -> sentinel (w=0)
          eval_one(gsel, packf, featf, px, py, pz, acc);
        }
#pragma unroll
        for (int u = 0; u < 8; u++) idx[u] = idxN[u];
      }
    }

    size_t v = ((size_t)i * WW + j) * DD + k;
    float4* o = out + v * 8;
#pragma unroll
    for (int f = 0; f < 8; f++) o[f] = acc[f];
  }
}

extern "C" void kernel_launch(void* const* d_in, const int* in_sizes, int n_in,
                              void* d_out, int out_size, void* d_ws, size_t ws_size,
                              hipStream_t stream) {
  const float* means  = (const float*)d_in[0];
  const float* opac   = (const float*)d_in[1];
  const float* scales = (const float*)d_in[2];
  const float* rots   = (const float*)d_in[3];
  const float* featf  = (const float*)d_in[4];

  char* ws = (char*)d_ws;
  float* packf  = (float*)ws;                   // (NG+1)*64 B = 524 KB
  int* tileCnt  = (int*)(ws + 528 * 1024);      // 25.6 KB
  int* tileList = (int*)(ws + 576 * 1024);      // 3.28 MB
  float4* outv  = (float4*)d_out;

  void* args[] = {(void*)&means, (void*)&opac, (void*)&scales, (void*)&rots,
                  (void*)&featf, (void*)&packf, (void*)&tileCnt,
                  (void*)&tileList, (void*)&outv};
  hipLaunchCooperativeKernel((const void*)gv_fused, dim3(BLOCKS), dim3(TPB),
                             args, 0, stream);
}

// Round 7
// 136.941 us; speedup vs baseline: 4.1998x; 4.1998x over previous
//
#include <hip/hip_runtime.h>

#define HH 160
#define WW 160
#define DD 16
#define NG 8192
#define VOXEL 0.4f

// tiles: 40 x 40 x 4, each 4x4x4 voxels = 6400 tiles, one WAVE (=block) per tile
#define TTX 40
#define TTY 40
#define TTZ 4
#define NTILES (TTX * TTY * TTZ)
#define CAP 128   // lambda ~26 survivors/tile; P(>128) ~ 0

// d_ws layout:
//   pack     : 8192 * 4 float4 (64 B/gaussian)  = 512 KB  @ 0
//   tileCnt  : NTILES int (25.6 KB)              @ 512 KB
//   tileList : NTILES * CAP int (3.28 MB)        @ 544 KB
// pack record (4 float4):
//   [0] = (mu.x, mu.y, mu.z, opacity)
//   [1] = (3sx,  3sy,  3sz,  ci00)
//   [2] = (ci01, ci02, ci11, ci12)
//   [3] = (ci22, 0, 0, 0)

__global__ __launch_bounds__(64) void gv_precompute_bin(
    const float* __restrict__ means, const float* __restrict__ opac,
    const float* __restrict__ scales, const float* __restrict__ rots,
    float4* __restrict__ pack, int* __restrict__ tileCnt,
    int* __restrict__ tileList) {
  int g = blockIdx.x * 64 + threadIdx.x;
  if (g >= NG) return;
  float qw = rots[g * 4 + 0], qx = rots[g * 4 + 1];
  float qy = rots[g * 4 + 2], qz = rots[g * 4 + 3];
  float inv = rsqrtf(qw * qw + qx * qx + qy * qy + qz * qz);
  qw *= inv; qx *= inv; qy *= inv; qz *= inv;
  float R[3][3];
  R[0][0] = 1.f - 2.f * (qy * qy + qz * qz);
  R[0][1] = 2.f * (qx * qy - qw * qz);
  R[0][2] = 2.f * (qx * qz + qw * qy);
  R[1][0] = 2.f * (qx * qy + qw * qz);
  R[1][1] = 1.f - 2.f * (qx * qx + qz * qz);
  R[1][2] = 2.f * (qy * qz - qw * qx);
  R[2][0] = 2.f * (qx * qz - qw * qy);
  R[2][1] = 2.f * (qy * qz + qw * qx);
  R[2][2] = 1.f - 2.f * (qx * qx + qy * qy);
  float sx = scales[g * 3 + 0], sy = scales[g * 3 + 1], sz = scales[g * 3 + 2];
  float s2[3] = {sx * sx, sy * sy, sz * sz};
  float is2[3] = {1.f / s2[0], 1.f / s2[1], 1.f / s2[2]};
  float cov00 = 0.f, cov11 = 0.f, cov22 = 0.f;
  float ci00 = 0.f, ci01 = 0.f, ci02 = 0.f, ci11 = 0.f, ci12 = 0.f, ci22 = 0.f;
#pragma unroll
  for (int c = 0; c < 3; c++) {
    cov00 += R[0][c] * R[0][c] * s2[c];
    cov11 += R[1][c] * R[1][c] * s2[c];
    cov22 += R[2][c] * R[2][c] * s2[c];
    ci00 += R[0][c] * R[0][c] * is2[c];
    ci01 += R[0][c] * R[1][c] * is2[c];
    ci02 += R[0][c] * R[2][c] * is2[c];
    ci11 += R[1][c] * R[1][c] * is2[c];
    ci12 += R[1][c] * R[2][c] * is2[c];
    ci22 += R[2][c] * R[2][c] * is2[c];
  }
  float mx = means[g * 3 + 0], my = means[g * 3 + 1], mz = means[g * 3 + 2];
  float bx = 3.f * sqrtf(cov00), by = 3.f * sqrtf(cov11), bz = 3.f * sqrtf(cov22);
  float4* p = pack + (size_t)g * 4;
  p[0] = make_float4(mx, my, mz, opac[g]);
  p[1] = make_float4(bx, by, bz, ci00);
  p[2] = make_float4(ci01, ci02, ci11, ci12);
  p[3] = make_float4(ci22, 0.f, 0.f, 0.f);

  // voxel-center index ranges covered by bbox (with float-slop margin)
  const float eps = 1e-4f;
  int i0 = (int)ceilf((mx - bx + 32.f) * 2.5f - 0.5f - eps);
  int i1 = (int)floorf((mx + bx + 32.f) * 2.5f - 0.5f + eps);
  int j0 = (int)ceilf((my - by + 32.f) * 2.5f - 0.5f - eps);
  int j1 = (int)floorf((my + by + 32.f) * 2.5f - 0.5f + eps);
  int k0 = (int)ceilf((mz - bz + 1.f) * 2.5f - 0.5f - eps);
  int k1 = (int)floorf((mz + bz + 1.f) * 2.5f - 0.5f + eps);
  i0 = max(i0, 0); i1 = min(i1, HH - 1);
  j0 = max(j0, 0); j1 = min(j1, WW - 1);
  k0 = max(k0, 0); k1 = min(k1, DD - 1);
  if (i0 > i1 || j0 > j1 || k0 > k1) return;
  int ti0 = i0 >> 2, ti1 = i1 >> 2;
  int tj0 = j0 >> 2, tj1 = j1 >> 2;
  int tk0 = k0 >> 2, tk1 = k1 >> 2;
  for (int ti = ti0; ti <= ti1; ti++)
    for (int tj = tj0; tj <= tj1; tj++)
      for (int tk = tk0; tk <= tk1; tk++) {
        int t = (ti * TTY + tj) * TTZ + tk;
        int pos = atomicAdd(&tileCnt[t], 1);
        if (pos < CAP) tileList[t * CAP + pos] = g;
      }
}

// One WAVE (= one 64-thread block) per 4x4x4 tile. Chunks of 32 survivors are
// staged into LDS with coalesced float4 loads (6 per lane, branch-free), then
// evaluated with uniform-address (broadcast, conflict-free) ds_reads and a
// branch-free body. __syncthreads on a 1-wave block is ~free.
__global__ __launch_bounds__(64, 4) void gv_voxelize(
    const float4* __restrict__ packv, const float4* __restrict__ featv,
    const int* __restrict__ tileCnt, const int* __restrict__ tileList,
    float4* __restrict__ out) {
  __shared__ int s_gi[32];
  __shared__ float4 s_d[32 * 12];   // per survivor: 4 pack + 8 feat float4s

  int lane = threadIdx.x;
  int t = blockIdx.x;
  int ti = t / (TTY * TTZ);
  int rem = t - ti * (TTY * TTZ);
  int tj = rem / TTZ;
  int tk = rem - tj * TTZ;
  int di = (lane >> 4) & 3, dj = (lane >> 2) & 3, dk = lane & 3;
  int i = ti * 4 + di, j = tj * 4 + dj, k = tk * 4 + dk;

  float px = (i + 0.5f) * VOXEL - 32.f;
  float py = (j + 0.5f) * VOXEL - 32.f;
  float pz = (k + 0.5f) * VOXEL - 1.f;

  int cnt = min(tileCnt[t], CAP);
  const int* lst = tileList + t * CAP;

  float4 acc[8];
#pragma unroll
  for (int f = 0; f < 8; f++) acc[f] = make_float4(0.f, 0.f, 0.f, 0.f);

  for (int base = 0; base < cnt; base += 32) {
    int m = min(32, cnt - base);
    __syncthreads();                 // protect s_gi/s_d from prev chunk readers
    if (lane < 32) s_gi[lane] = lst[base + min(lane, m - 1)];
    __syncthreads();

    // stage 32 survivors x 12 float4 = 384 float4 with 6 loads/lane
#pragma unroll
    for (int r = 0; r < 6; r++) {
      int idx = lane + 64 * r;
      int s = idx / 12;
      int piece = idx - s * 12;
      int gg = s_gi[s];
      const float4* src = (piece < 4)
          ? (packv + (size_t)gg * 4 + piece)
          : (featv + (size_t)gg * 8 + (piece - 4));
      s_d[idx] = *src;
    }
    __syncthreads();

#pragma unroll 2
    for (int n = 0; n < m; n++) {
      const float4* sp = s_d + n * 12;
      float4 p0 = sp[0], p1 = sp[1], p2 = sp[2], p3 = sp[3];
      float dx = px - p0.x, dy = py - p0.y, dz = pz - p0.z;
      bool in = (fabsf(dx) <= p1.x) & (fabsf(dy) <= p1.y) & (fabsf(dz) <= p1.z);
      float maha = p1.w * dx * dx + p2.z * dy * dy + p3.x * dz * dz +
                   2.f * (p2.x * dx * dy + p2.y * dx * dz + p2.w * dy * dz);
      float w = in ? p0.w * __expf(-0.5f * maha) : 0.f;
#pragma unroll
      for (int f = 0; f < 8; f++) {
        float4 fv = sp[4 + f];
        acc[f].x += w * fv.x;
        acc[f].y += w * fv.y;
        acc[f].z += w * fv.z;
        acc[f].w += w * fv.w;
      }
    }
  }

  size_t v = ((size_t)i * WW + j) * DD + k;
  float4* o = out + v * 8;
#pragma unroll
  for (int f = 0; f < 8; f++) o[f] = acc[f];
}

extern "C" void kernel_launch(void* const* d_in, const int* in_sizes, int n_in,
                              void* d_out, int out_size, void* d_ws, size_t ws_size,
                              hipStream_t stream) {
  const float* means  = (const float*)d_in[0];
  const float* opac   = (const float*)d_in[1];
  const float* scales = (const float*)d_in[2];
  const float* rots   = (const float*)d_in[3];
  const float4* featv = (const float4*)d_in[4];

  char* ws = (char*)d_ws;
  float4* pack   = (float4*)ws;                       // 512 KB
  int* tileCnt   = (int*)(ws + 512 * 1024);           // 25.6 KB
  int* tileList  = (int*)(ws + 544 * 1024);           // 3.28 MB

  hipMemsetAsync(tileCnt, 0, NTILES * sizeof(int), stream);
  gv_precompute_bin<<<NG / 64, 64, 0, stream>>>(means, opac, scales, rots,
                                                pack, tileCnt, tileList);
  gv_voxelize<<<NTILES, 64, 0, stream>>>(pack, featv, tileCnt, tileList,
                                         (float4*)d_out);
}